// Round 11
// baseline (187.918 us; speedup 1.0000x reference)
//
#include <hip/hip_runtime.h>
#include <cstdint>
#include <cstddef>

#define S 8192
#define Dm 1024
#define E 64
#define CAP 128
#define SEC 67108864ull   // S*E*CAP
// out layout (float32 elements), out_size = 1 + 2*SEC + 64 = 134,217,793:
//   [0] l_aux | [1,1+SEC) combine | [1+SEC,1+2SEC) dispatch | [1+2SEC,+64) counts
// Coverage map (every element written every call):
//   k_fillscan fill blocks: chunks [1, 33554432) = elements [4, 134217728) = 0
//   k_fillscan scan blk0:   elements 1,2,3 and 134217728 (=out[2SEC]) = 0
//   k_fillscan scan blk e:  counts out[1+2SEC+e]
//   k_scatter:              sparse combine/dispatch overwrites; out[0] = l_aux

#define GEMM_BLOCKS 256   // 32 tokens x 64 experts each (R8 champion GEMM)
#define SCAN_BLOCKS 64
#define FILL_BLOCKS 1984  // 64+1984 = 2048
#define N4F 33554432u     // fill chunk bound: elements [4, 134217728)

typedef float f32x4 __attribute__((ext_vector_type(4)));

// ---------------- K1: GEMM + softmax/argmax (R8 code, no fill branch) --------
__global__ __launch_bounds__(256) void k_gemm(const float* __restrict__ x,
                                              const float* __restrict__ w,
                                              float* __restrict__ gate,
                                              int* __restrict__ idx,
                                              float* __restrict__ me_part) {
    int bid = blockIdx.x;
    int tid = threadIdx.x;
    __shared__ float Al[32][66];   // row 264B: float2-aligned, 2-way max
    __shared__ float Wl[64][68];   // row 272B: float4-aligned
    __shared__ float sm[32];
    __shared__ float sinv[32];
    int tok = tid & 31;
    int eo = tid >> 5;
    int t0 = bid * 32;
    const float* asrc = x + (size_t)(t0 + (tid >> 3)) * Dm + (tid & 7) * 8;
    const float* wsrc0 = w + (size_t)(tid >> 3) * Dm + (tid & 7) * 8;
    const float* wsrc1 = wsrc0 + 32 * (size_t)Dm;
    float* adst = &Al[tid >> 3][(tid & 7) * 8];
    float* wdst0 = &Wl[tid >> 3][(tid & 7) * 8];
    float* wdst1 = &Wl[32 + (tid >> 3)][(tid & 7) * 8];

    float acc[8] = {0.f, 0.f, 0.f, 0.f, 0.f, 0.f, 0.f, 0.f};
    float4 pa0 = *(const float4*)(asrc + 0);
    float4 pa1 = *(const float4*)(asrc + 4);
    float4 pw0 = *(const float4*)(wsrc0 + 0);
    float4 pw1 = *(const float4*)(wsrc0 + 4);
    float4 pw2 = *(const float4*)(wsrc1 + 0);
    float4 pw3 = *(const float4*)(wsrc1 + 4);

    for (int ch = 0; ch < 16; ++ch) {
        __syncthreads();
        *(float2*)(adst + 0) = make_float2(pa0.x, pa0.y);
        *(float2*)(adst + 2) = make_float2(pa0.z, pa0.w);
        *(float2*)(adst + 4) = make_float2(pa1.x, pa1.y);
        *(float2*)(adst + 6) = make_float2(pa1.z, pa1.w);
        *(float4*)(wdst0 + 0) = pw0;
        *(float4*)(wdst0 + 4) = pw1;
        *(float4*)(wdst1 + 0) = pw2;
        *(float4*)(wdst1 + 4) = pw3;
        __syncthreads();
        if (ch < 15) {
            int kb = (ch + 1) * 64;
            pa0 = *(const float4*)(asrc + kb);
            pa1 = *(const float4*)(asrc + kb + 4);
            pw0 = *(const float4*)(wsrc0 + kb);
            pw1 = *(const float4*)(wsrc0 + kb + 4);
            pw2 = *(const float4*)(wsrc1 + kb);
            pw3 = *(const float4*)(wsrc1 + kb + 4);
        }
#pragma unroll 4
        for (int k4 = 0; k4 < 16; ++k4) {
            float2 aa = *(const float2*)&Al[tok][k4 * 4];
            float2 ab = *(const float2*)&Al[tok][k4 * 4 + 2];
#pragma unroll
            for (int j = 0; j < 8; ++j) {
                float4 wv = *(const float4*)&Wl[eo * 8 + j][k4 * 4];
                acc[j] = fmaf(ab.y, wv.w, fmaf(ab.x, wv.z,
                         fmaf(aa.y, wv.y, fmaf(aa.x, wv.x, acc[j]))));
            }
        }
    }
    __syncthreads();
#pragma unroll
    for (int j = 0; j < 8; ++j) Al[tok][eo * 8 + j] = acc[j];
    __syncthreads();
    if (tid < 32) {   // first-index argmax + exp-sum
        float m = Al[tid][0];
        int am = 0;
#pragma unroll
        for (int c = 1; c < E; ++c) {
            float v = Al[tid][c];
            if (v > m) { m = v; am = c; }
        }
        float ssum = 0.f;
#pragma unroll
        for (int c = 0; c < E; ++c) ssum += __expf(Al[tid][c] - m);
        float inv = 1.0f / ssum;
        gate[t0 + tid] = inv;
        idx[t0 + tid] = am;
        sm[tid] = m;
        sinv[tid] = inv;
    }
    __syncthreads();
    if (tid < E) {    // partial me column sums (deterministic)
        float cs = 0.f;
#pragma unroll 8
        for (int r = 0; r < 32; ++r)
            cs += __expf(Al[r][tid] - sm[r]) * sinv[r];
        me_part[bid * E + tid] = cs;
    }
}

// ---------------- K2: 537MB zero-fill with the expert scan hidden inside -----
// Blocks [0,64): per-expert ordered ballot scan (R8's proven code) -> tg[t] =
//   {off_in_token or -1, gate}; counts; me-reduce -> la_part. Runs ~4us while
//   the 1984 fill blocks stream ~85us of zeros — fully hidden, races excluded
//   by region partition (scan writes tg/la_part/counts/boundary only).
// Blocks [64,2048): grid-stride float4 zero of elements [4, 134217728).
__global__ __launch_bounds__(256) void k_fillscan(const int* __restrict__ idx,
                                                  const float* __restrict__ gate,
                                                  const float* __restrict__ me_part,
                                                  float2* __restrict__ tg,
                                                  float* __restrict__ la_part,
                                                  float* __restrict__ out) {
    int bid = blockIdx.x;
    int tid = threadIdx.x;
    if (bid < SCAN_BLOCKS) {
        __shared__ int wsum[4];
        __shared__ float red[256];
        int e = bid;
        int lane = tid & 63;
        int wid = tid >> 6;
        if (bid == 0 && tid == 0) {   // boundary elements not covered by fill
            out[1] = 0.f; out[2] = 0.f; out[3] = 0.f;
            out[2 * SEC] = 0.f;
        }
        int running = 0;
        for (int ch = 0; ch < S / 256; ++ch) {
            int t = ch * 256 + tid;
            bool f = (idx[t] == e);
            unsigned long long b = __ballot(f);
            int pre = __popcll(b & ((1ull << lane) - 1ull));
            if (lane == 0) wsum[wid] = __popcll(b);
            __syncthreads();
            int off = running;
#pragma unroll
            for (int w2 = 0; w2 < 4; ++w2)
                if (w2 < wid) off += wsum[w2];
            int p = off + pre;
            if (f) {   // every token written by exactly its argmax expert
                int tgt = (p < CAP) ? e * CAP + p : -1;
                tg[t] = make_float2(__int_as_float(tgt), gate[t]);
            }
            running += wsum[0] + wsum[1] + wsum[2] + wsum[3];
            __syncthreads();
        }
        // me reduction over 256 GEMM blocks
        red[tid] = me_part[tid * E + e];
        __syncthreads();
        for (int s2 = 128; s2 > 0; s2 >>= 1) {
            if (tid < s2) red[tid] += red[tid + s2];
            __syncthreads();
        }
        if (tid == 0) {
            out[1 + 2 * SEC + e] = (float)running;   // exp_counts (pre-drop)
            la_part[e] = red[0] * (1.0f / (float)S) *
                         ((float)running / (float)S) * (float)E;
        }
    } else {
        int fb = bid - SCAN_BLOCKS;
        f32x4 z = {0.f, 0.f, 0.f, 0.f};
        f32x4* o4 = (f32x4*)out;
        for (unsigned i = 1u + (unsigned)fb * 256u + tid; i < N4F;
             i += FILL_BLOCKS * 256u)
            o4[i] = z;
    }
}

// ---------------- K3: sparse scatter + l_aux ----------------
// Blocks [0,32): token t = gid; write combine/dispatch pair if kept.
// Block 32: reduce la_part -> out[0].
__global__ __launch_bounds__(256) void k_scatter(const float2* __restrict__ tg,
                                                 const float* __restrict__ la_part,
                                                 float* __restrict__ out) {
    int bid = blockIdx.x;
    int tid = threadIdx.x;
    if (bid == 32) {
        if (tid < E) {
            float la = la_part[tid];
#pragma unroll
            for (int off = 32; off > 0; off >>= 1)
                la += __shfl_down(la, off, 64);
            if (tid == 0) out[0] = la;
        }
        return;
    }
    int t = bid * 256 + tid;
    float2 g = tg[t];
    int tgt = __float_as_int(g.x);
    if (tgt >= 0) {
        size_t o = 1 + (size_t)t * (E * CAP) + (size_t)tgt;
        out[o] = g.y;                 // combine_weights
        out[o + SEC] = 1.0f;          // dispatch_mask
    }
}

extern "C" void kernel_launch(void* const* d_in, const int* in_sizes, int n_in,
                              void* d_out, int out_size, void* d_ws, size_t ws_size,
                              hipStream_t stream) {
    const float* x = (const float*)d_in[0];      // [S, Dm] fp32
    const float* w = (const float*)d_in[1];      // [E, Dm] fp32
    float* out = (float*)d_out;

    // ws layout
    float* me_part = (float*)d_ws;               // [256][64] = 64 KB
    float* gate = me_part + GEMM_BLOCKS * E;     // S floats
    int* idx = (int*)(gate + S);                 // S ints
    float2* tg = (float2*)(idx + S);             // S float2 = 64 KB
    float* la_part = (float*)(tg + S);           // 64 floats

    k_gemm<<<dim3(GEMM_BLOCKS), dim3(256), 0, stream>>>(x, w, gate, idx, me_part);
    k_fillscan<<<dim3(SCAN_BLOCKS + FILL_BLOCKS), dim3(256), 0, stream>>>(
        idx, gate, me_part, tg, la_part, out);
    k_scatter<<<dim3(33), dim3(256), 0, stream>>>(tg, la_part, out);
}

// Round 12
// 146.706 us; speedup vs baseline: 1.2809x; 1.2809x over previous
//
#include <hip/hip_runtime.h>
#include <cstdint>
#include <cstddef>

#define S 8192
#define Dm 1024
#define E 64
#define CAP 128
#define SEC 67108864ull   // S*E*CAP
// out layout (float32 elements), out_size = 1 + 2*SEC + 64 = 134,217,793:
//   [0] l_aux | [1,1+SEC) combine | [1+SEC,1+2SEC) dispatch | [1+2SEC,+64) counts
// Coverage: K1 fill zeroes elements [0,134217792) (incl. out[0], which k_scan
// atomicAdds l_aux into); leftover element 134217792 = counts[63] is written
// unconditionally by k_scan.

#define GEMM_BLOCKS 256   // 32 tokens x 64 experts, 512 thr = 2 K-half groups
#define FILL_BLOCKS 512
#define NTHR 512
#define N4ALL 33554448u

typedef float f32x4 __attribute__((ext_vector_type(4)));

// ---------------- K1: fused {8-wave K-split GEMM+softmax} + 537MB fill -------
// GEMM blocks [0,256): R8's proven tile, but 512 threads: wave-group g = K-half.
//   Each group stages its own A(32x64)/W(64x64) slice into Al[g]/Wl[g] and
//   accumulates 8 chunks; partials reduced via LDS. Halves the dependent
//   chain, doubles waves/CU -> fixes the R11-diagnosed latency bound.
// Fill blocks [256,768): grid-stride float4 zero of elements [0,134217792).
// LDS 51KB -> 3 blocks/CU: per CU 1 GEMM (8 waves) + 2 fill (16 waves).
__global__ __launch_bounds__(512) void k_main(const float* __restrict__ x,
                                              const float* __restrict__ w,
                                              float* __restrict__ gate,
                                              int* __restrict__ idx,
                                              float* __restrict__ me_part,
                                              float* __restrict__ out) {
    int bid = blockIdx.x;
    int tid = threadIdx.x;
    if (bid < GEMM_BLOCKS) {
        __shared__ float Al[2][32][66];   // 16.9 KB
        __shared__ float Wl[2][64][68];   // 34.8 KB
        __shared__ float sm[32];
        __shared__ float sinv[32];
        int g = tid >> 8;              // K-half group 0/1
        int lt = tid & 255;            // thread within group
        int tok = lt & 31;             // local token
        int eo = lt >> 5;              // expert octet 0..7
        int t0 = bid * 32;
        int kb0 = g * 512;             // this group's K base
        const float* asrc = x + (size_t)(t0 + (lt >> 3)) * Dm + kb0 + (lt & 7) * 8;
        const float* wsrc0 = w + (size_t)(lt >> 3) * Dm + kb0 + (lt & 7) * 8;
        const float* wsrc1 = wsrc0 + 32 * (size_t)Dm;
        float* adst = &Al[g][lt >> 3][(lt & 7) * 8];
        float* wdst0 = &Wl[g][lt >> 3][(lt & 7) * 8];
        float* wdst1 = &Wl[g][32 + (lt >> 3)][(lt & 7) * 8];

        float acc[8] = {0.f, 0.f, 0.f, 0.f, 0.f, 0.f, 0.f, 0.f};
        float4 pa0 = *(const float4*)(asrc + 0);
        float4 pa1 = *(const float4*)(asrc + 4);
        float4 pw0 = *(const float4*)(wsrc0 + 0);
        float4 pw1 = *(const float4*)(wsrc0 + 4);
        float4 pw2 = *(const float4*)(wsrc1 + 0);
        float4 pw3 = *(const float4*)(wsrc1 + 4);

        for (int ch = 0; ch < 8; ++ch) {
            __syncthreads();           // previous compute done; LDS writable
            *(float2*)(adst + 0) = make_float2(pa0.x, pa0.y);
            *(float2*)(adst + 2) = make_float2(pa0.z, pa0.w);
            *(float2*)(adst + 4) = make_float2(pa1.x, pa1.y);
            *(float2*)(adst + 6) = make_float2(pa1.z, pa1.w);
            *(float4*)(wdst0 + 0) = pw0;
            *(float4*)(wdst0 + 4) = pw1;
            *(float4*)(wdst1 + 0) = pw2;
            *(float4*)(wdst1 + 4) = pw3;
            __syncthreads();           // LDS ready
            if (ch < 7) {              // issue next chunk's loads (hidden)
                int kb = (ch + 1) * 64;
                pa0 = *(const float4*)(asrc + kb);
                pa1 = *(const float4*)(asrc + kb + 4);
                pw0 = *(const float4*)(wsrc0 + kb);
                pw1 = *(const float4*)(wsrc0 + kb + 4);
                pw2 = *(const float4*)(wsrc1 + kb);
                pw3 = *(const float4*)(wsrc1 + kb + 4);
            }
            // LDS-only inner loop: per k4 = 2 b64 (A) + 8 b128 (W, half-wave
            // broadcast) + 32 FMA
#pragma unroll 4
            for (int k4 = 0; k4 < 16; ++k4) {
                float2 aa = *(const float2*)&Al[g][tok][k4 * 4];
                float2 ab = *(const float2*)&Al[g][tok][k4 * 4 + 2];
#pragma unroll
                for (int j = 0; j < 8; ++j) {
                    float4 wv = *(const float4*)&Wl[g][eo * 8 + j][k4 * 4];
                    acc[j] = fmaf(ab.y, wv.w, fmaf(ab.x, wv.z,
                             fmaf(aa.y, wv.y, fmaf(aa.x, wv.x, acc[j]))));
                }
            }
        }
        __syncthreads();
        // ---- K-half reduction through LDS, then softmax/argmax ----
        if (g == 1) {
#pragma unroll
            for (int j = 0; j < 8; ++j) Al[1][tok][eo * 8 + j] = acc[j];
        }
        __syncthreads();
        if (g == 0) {
#pragma unroll
            for (int j = 0; j < 8; ++j)
                Al[0][tok][eo * 8 + j] = acc[j] + Al[1][tok][eo * 8 + j];
        }
        __syncthreads();
        if (tid < 32) {   // row phase: first-index argmax + exp-sum
            float m = Al[0][tid][0];
            int am = 0;
#pragma unroll
            for (int c = 1; c < E; ++c) {
                float v = Al[0][tid][c];
                if (v > m) { m = v; am = c; }
            }
            float ssum = 0.f;
#pragma unroll
            for (int c = 0; c < E; ++c) ssum += __expf(Al[0][tid][c] - m);
            float inv = 1.0f / ssum;   // softmax value at the argmax
            gate[t0 + tid] = inv;
            idx[t0 + tid] = am;
            sm[tid] = m;
            sinv[tid] = inv;
        }
        __syncthreads();
        if (tid < E) {    // column phase: partial me sums (deterministic)
            float cs = 0.f;
#pragma unroll 8
            for (int r = 0; r < 32; ++r)
                cs += __expf(Al[0][r][tid] - sm[r]) * sinv[r];
            me_part[bid * E + tid] = cs;
        }
    } else {
        int fb = bid - GEMM_BLOCKS;
        f32x4 z = {0.f, 0.f, 0.f, 0.f};
        f32x4* o4 = (f32x4*)out;
        for (unsigned i = (unsigned)fb * NTHR + tid; i < N4ALL;
             i += FILL_BLOCKS * NTHR)
            o4[i] = z;
    }
}

// ---------------- K2: ordered scan + scatter + counts + me-reduce + l_aux ----
// R8's proven kernel, verbatim. 64 blocks (one per expert) x 256 threads.
__global__ __launch_bounds__(256) void k_scan(const int* __restrict__ idx,
                                              const float* __restrict__ gate,
                                              const float* __restrict__ me_part,
                                              float* __restrict__ out) {
    int e = blockIdx.x;
    int tid = threadIdx.x;
    int lane = tid & 63;
    int wid = tid >> 6;
    __shared__ int wsum[4];
    __shared__ float red[256];
    int running = 0;
    for (int ch = 0; ch < S / 256; ++ch) {
        int t = ch * 256 + tid;
        bool f = (idx[t] == e);
        unsigned long long b = __ballot(f);
        int pre = __popcll(b & ((1ull << lane) - 1ull));
        if (lane == 0) wsum[wid] = __popcll(b);
        __syncthreads();
        int off = running;
#pragma unroll
        for (int w2 = 0; w2 < 4; ++w2)
            if (w2 < wid) off += wsum[w2];
        int p = off + pre;
        if (f && p < CAP) {
            size_t o = 1 + (size_t)t * (E * CAP) + (size_t)e * CAP + (size_t)p;
            out[o] = gate[t];                 // combine_weights
            out[o + (size_t)SEC] = 1.0f;      // dispatch_mask
        }
        running += wsum[0] + wsum[1] + wsum[2] + wsum[3];
        __syncthreads();
    }
    // me reduction: me_sum[e] = sum over 256 GEMM blocks' partials
    red[tid] = me_part[tid * E + e];
    __syncthreads();
    for (int s2 = 128; s2 > 0; s2 >>= 1) {
        if (tid < s2) red[tid] += red[tid + s2];
        __syncthreads();
    }
    if (tid == 0) {
        out[1 + 2 * (size_t)SEC + e] = (float)running;   // exp_counts (pre-drop)
        float la = red[0] * (1.0f / (float)S) *
                   ((float)running / (float)S) * (float)E;
        atomicAdd(out, la);                              // l_aux
    }
}

extern "C" void kernel_launch(void* const* d_in, const int* in_sizes, int n_in,
                              void* d_out, int out_size, void* d_ws, size_t ws_size,
                              hipStream_t stream) {
    const float* x = (const float*)d_in[0];      // [S, Dm] fp32
    const float* w = (const float*)d_in[1];      // [E, Dm] fp32
    float* out = (float*)d_out;

    // ws layout
    float* me_part = (float*)d_ws;               // [256][64] = 64 KB
    float* gate = me_part + GEMM_BLOCKS * E;     // S floats
    int* idx = (int*)(gate + S);                 // S ints
    float* me_sum = (float*)(idx + S);           // (unused scratch)
    (void)me_sum;

    k_main<<<dim3(GEMM_BLOCKS + FILL_BLOCKS), dim3(NTHR), 0, stream>>>(
        x, w, gate, idx, me_part, out);
    k_scan<<<dim3(64), dim3(256), 0, stream>>>(idx, gate, me_part, out);
}

// Round 13
// 138.286 us; speedup vs baseline: 1.3589x; 1.0609x over previous
//
#include <hip/hip_runtime.h>
#include <cstdint>
#include <cstddef>

#define S 8192
#define Dm 1024
#define E 64
#define CAP 128
#define SEC 67108864ull   // S*E*CAP
// out layout (float32 elements), out_size = 1 + 2*SEC + 64 = 134,217,793:
//   [0] l_aux | [1,1+SEC) combine | [1+SEC,1+2SEC) dispatch | [1+2SEC,+64) counts
// K1 fill zeroes elements [0,134217792); leftover element = counts[63] is
// written unconditionally by k_scan.

#define GEMM_BLOCKS 256   // 32 tokens x 64 experts each
#define FILL_BLOCKS 1792  // grid 2048
#define N4ALL 33554448u

typedef float f32x4 __attribute__((ext_vector_type(4)));

// ---------------- K1: fused {GEMM+softmax+argmax} + 537MB zero-fill ----------
// R8 champion, ONE change: thread->output remap (2 tok x 4 exp), which cuts
// LDS traffic from 144B/32FMA to 96B/32FMA (R12 post-mortem: the GEMM is
// LDS-read-throughput-bound; the per-CU LDS pipe was the wall).
__global__ __launch_bounds__(256) void k_main(const float* __restrict__ x,
                                              const float* __restrict__ w,
                                              float* __restrict__ gate,
                                              int* __restrict__ idx,
                                              float* __restrict__ me_part,
                                              float* __restrict__ out) {
    int bid = blockIdx.x;
    int tid = threadIdx.x;
    if (bid < GEMM_BLOCKS) {
        __shared__ float Al[32][68];   // 272B rows: 16B-aligned (b128 A reads)
        __shared__ float Wl[64][68];   // 272B rows: 16B-aligned
        __shared__ float sm[32];
        __shared__ float sinv[32];
        int rt = (tid & 15) * 2;       // token pair base (0,2,..,30)
        int ce = (tid >> 4) * 4;       // expert quad base (0,4,..,60)
        int t0 = bid * 32;
        // staging maps (unchanged): thread -> row tid>>3, 8 floats at (tid&7)*8
        const float* asrc = x + (size_t)(t0 + (tid >> 3)) * Dm + (tid & 7) * 8;
        const float* wsrc0 = w + (size_t)(tid >> 3) * Dm + (tid & 7) * 8;
        const float* wsrc1 = wsrc0 + 32 * (size_t)Dm;
        float* adst = &Al[tid >> 3][(tid & 7) * 8];
        float* wdst0 = &Wl[tid >> 3][(tid & 7) * 8];
        float* wdst1 = &Wl[32 + (tid >> 3)][(tid & 7) * 8];

        float4 acc0 = make_float4(0.f, 0.f, 0.f, 0.f);  // token rt,   experts ce..ce+3
        float4 acc1 = make_float4(0.f, 0.f, 0.f, 0.f);  // token rt+1, experts ce..ce+3
        float4 pa0 = *(const float4*)(asrc + 0);
        float4 pa1 = *(const float4*)(asrc + 4);
        float4 pw0 = *(const float4*)(wsrc0 + 0);
        float4 pw1 = *(const float4*)(wsrc0 + 4);
        float4 pw2 = *(const float4*)(wsrc1 + 0);
        float4 pw3 = *(const float4*)(wsrc1 + 4);

        for (int ch = 0; ch < 16; ++ch) {
            __syncthreads();           // previous compute done; LDS writable
            *(float2*)(adst + 0) = make_float2(pa0.x, pa0.y);
            *(float2*)(adst + 2) = make_float2(pa0.z, pa0.w);
            *(float2*)(adst + 4) = make_float2(pa1.x, pa1.y);
            *(float2*)(adst + 6) = make_float2(pa1.z, pa1.w);
            *(float4*)(wdst0 + 0) = pw0;
            *(float4*)(wdst0 + 4) = pw1;
            *(float4*)(wdst1 + 0) = pw2;
            *(float4*)(wdst1 + 4) = pw3;
            __syncthreads();           // LDS ready
            if (ch < 15) {             // issue next chunk's loads (hidden)
                int kb = (ch + 1) * 64;
                pa0 = *(const float4*)(asrc + kb);
                pa1 = *(const float4*)(asrc + kb + 4);
                pw0 = *(const float4*)(wsrc0 + kb);
                pw1 = *(const float4*)(wsrc0 + kb + 4);
                pw2 = *(const float4*)(wsrc1 + kb);
                pw3 = *(const float4*)(wsrc1 + kb + 4);
            }
            // LDS inner loop: per k4 = 2 b128 (A: 2 tokens) + 4 b128 (W: 4
            // experts, 16-lane broadcast) + 32 FMA  [96B/32FMA vs R8's 144B]
#pragma unroll 4
            for (int k4 = 0; k4 < 16; ++k4) {
                float4 a0 = *(const float4*)&Al[rt][k4 * 4];
                float4 a1 = *(const float4*)&Al[rt + 1][k4 * 4];
                float4 w0 = *(const float4*)&Wl[ce + 0][k4 * 4];
                float4 w1 = *(const float4*)&Wl[ce + 1][k4 * 4];
                float4 w2 = *(const float4*)&Wl[ce + 2][k4 * 4];
                float4 w3 = *(const float4*)&Wl[ce + 3][k4 * 4];
                acc0.x = fmaf(a0.w, w0.w, fmaf(a0.z, w0.z, fmaf(a0.y, w0.y, fmaf(a0.x, w0.x, acc0.x))));
                acc0.y = fmaf(a0.w, w1.w, fmaf(a0.z, w1.z, fmaf(a0.y, w1.y, fmaf(a0.x, w1.x, acc0.y))));
                acc0.z = fmaf(a0.w, w2.w, fmaf(a0.z, w2.z, fmaf(a0.y, w2.y, fmaf(a0.x, w2.x, acc0.z))));
                acc0.w = fmaf(a0.w, w3.w, fmaf(a0.z, w3.z, fmaf(a0.y, w3.y, fmaf(a0.x, w3.x, acc0.w))));
                acc1.x = fmaf(a1.w, w0.w, fmaf(a1.z, w0.z, fmaf(a1.y, w0.y, fmaf(a1.x, w0.x, acc1.x))));
                acc1.y = fmaf(a1.w, w1.w, fmaf(a1.z, w1.z, fmaf(a1.y, w1.y, fmaf(a1.x, w1.x, acc1.y))));
                acc1.z = fmaf(a1.w, w2.w, fmaf(a1.z, w2.z, fmaf(a1.y, w2.y, fmaf(a1.x, w2.x, acc1.z))));
                acc1.w = fmaf(a1.w, w3.w, fmaf(a1.z, w3.z, fmaf(a1.y, w3.y, fmaf(a1.x, w3.x, acc1.w))));
            }
        }
        __syncthreads();
        // ---- epilogue: logits tile -> LDS (reuse Al), softmax/argmax ----
        Al[rt][ce + 0] = acc0.x; Al[rt][ce + 1] = acc0.y;
        Al[rt][ce + 2] = acc0.z; Al[rt][ce + 3] = acc0.w;
        Al[rt + 1][ce + 0] = acc1.x; Al[rt + 1][ce + 1] = acc1.y;
        Al[rt + 1][ce + 2] = acc1.z; Al[rt + 1][ce + 3] = acc1.w;
        __syncthreads();
        if (tid < 32) {   // row phase: first-index argmax + exp-sum
            float m = Al[tid][0];
            int am = 0;
#pragma unroll
            for (int c = 1; c < E; ++c) {
                float v = Al[tid][c];
                if (v > m) { m = v; am = c; }
            }
            float ssum = 0.f;
#pragma unroll
            for (int c = 0; c < E; ++c) ssum += __expf(Al[tid][c] - m);
            float inv = 1.0f / ssum;   // softmax value at the argmax
            gate[t0 + tid] = inv;
            idx[t0 + tid] = am;
            sm[tid] = m;
            sinv[tid] = inv;
        }
        __syncthreads();
        if (tid < E) {    // column phase: partial me sums (deterministic)
            float cs = 0.f;
#pragma unroll 8
            for (int r = 0; r < 32; ++r)
                cs += __expf(Al[r][tid] - sm[r]) * sinv[r];
            me_part[bid * E + tid] = cs;
        }
    } else {
        int fb = bid - GEMM_BLOCKS;
        f32x4 z = {0.f, 0.f, 0.f, 0.f};
        f32x4* o4 = (f32x4*)out;
        for (unsigned i = (unsigned)fb * 256u + tid; i < N4ALL;
             i += FILL_BLOCKS * 256u)
            o4[i] = z;
    }
}

// ---------------- K2: ordered scan + scatter + counts + me-reduce + l_aux ----
// R8's proven kernel, verbatim. 64 blocks (one per expert) x 256 threads.
__global__ __launch_bounds__(256) void k_scan(const int* __restrict__ idx,
                                              const float* __restrict__ gate,
                                              const float* __restrict__ me_part,
                                              float* __restrict__ out) {
    int e = blockIdx.x;
    int tid = threadIdx.x;
    int lane = tid & 63;
    int wid = tid >> 6;
    __shared__ int wsum[4];
    __shared__ float red[256];
    int running = 0;
    for (int ch = 0; ch < S / 256; ++ch) {
        int t = ch * 256 + tid;
        bool f = (idx[t] == e);
        unsigned long long b = __ballot(f);
        int pre = __popcll(b & ((1ull << lane) - 1ull));
        if (lane == 0) wsum[wid] = __popcll(b);
        __syncthreads();
        int off = running;
#pragma unroll
        for (int w2 = 0; w2 < 4; ++w2)
            if (w2 < wid) off += wsum[w2];
        int p = off + pre;
        if (f && p < CAP) {
            size_t o = 1 + (size_t)t * (E * CAP) + (size_t)e * CAP + (size_t)p;
            out[o] = gate[t];                 // combine_weights
            out[o + (size_t)SEC] = 1.0f;      // dispatch_mask
        }
        running += wsum[0] + wsum[1] + wsum[2] + wsum[3];
        __syncthreads();
    }
    // me reduction: me_sum[e] = sum over 256 GEMM blocks' partials
    red[tid] = me_part[tid * E + e];
    __syncthreads();
    for (int s2 = 128; s2 > 0; s2 >>= 1) {
        if (tid < s2) red[tid] += red[tid + s2];
        __syncthreads();
    }
    if (tid == 0) {
        out[1 + 2 * (size_t)SEC + e] = (float)running;   // exp_counts (pre-drop)
        float la = red[0] * (1.0f / (float)S) *
                   ((float)running / (float)S) * (float)E;
        atomicAdd(out, la);                              // l_aux
    }
}

extern "C" void kernel_launch(void* const* d_in, const int* in_sizes, int n_in,
                              void* d_out, int out_size, void* d_ws, size_t ws_size,
                              hipStream_t stream) {
    const float* x = (const float*)d_in[0];      // [S, Dm] fp32
    const float* w = (const float*)d_in[1];      // [E, Dm] fp32
    float* out = (float*)d_out;

    // ws layout
    float* me_part = (float*)d_ws;               // [256][64] = 64 KB
    float* gate = me_part + GEMM_BLOCKS * E;     // S floats
    int* idx = (int*)(gate + S);                 // S ints

    k_main<<<dim3(GEMM_BLOCKS + FILL_BLOCKS), dim3(256), 0, stream>>>(
        x, w, gate, idx, me_part, out);
    k_scan<<<dim3(64), dim3(256), 0, stream>>>(idx, gate, me_part, out);
}

// Round 14
// 136.116 us; speedup vs baseline: 1.3806x; 1.0159x over previous
//
#include <hip/hip_runtime.h>
#include <cstdint>
#include <cstddef>

#define S 8192
#define Dm 1024
#define E 64
#define CAP 128
#define SEC 67108864ull   // S*E*CAP
// out layout (float32 elements), out_size = 1 + 2*SEC + 64 = 134,217,793:
//   [0] l_aux | [1,1+SEC) combine | [1+SEC,1+2SEC) dispatch | [1+2SEC,+64) counts
// K1 fill zeroes elements [0,134217792); leftover element = counts[63] is
// written unconditionally by k_scan.

#define GEMM_BLOCKS 256   // 32 tokens x 64 experts each
#define FILL_BLOCKS 1792  // grid 2048
#define N4ALL 33554448u

typedef float f32x4 __attribute__((ext_vector_type(4)));

// ---------------- K1: fused {GEMM+softmax+argmax} + 537MB zero-fill ----------
// R13 champion, ONE change: 2-DEEP register prefetch (even/odd chunk sets).
// Theory: under the saturated fill the CU's VMEM queue is full of fill
// stores; GEMM staging loads wait O(5-10K cyc) — longer than the 1-chunk
// (~4600 cyc) prefetch distance — exposing a stall each chunk barrier.
// 2 chunks of distance (~9200 cyc) covers the congested queue latency.
__global__ __launch_bounds__(256) void k_main(const float* __restrict__ x,
                                              const float* __restrict__ w,
                                              float* __restrict__ gate,
                                              int* __restrict__ idx,
                                              float* __restrict__ me_part,
                                              float* __restrict__ out) {
    int bid = blockIdx.x;
    int tid = threadIdx.x;
    if (bid < GEMM_BLOCKS) {
        __shared__ float Al[32][68];   // 272B rows: 16B-aligned (b128 reads)
        __shared__ float Wl[64][68];
        __shared__ float sm[32];
        __shared__ float sinv[32];
        int rt = (tid & 15) * 2;       // token pair base
        int ce = (tid >> 4) * 4;       // expert quad base
        int t0 = bid * 32;
        const float* asrc = x + (size_t)(t0 + (tid >> 3)) * Dm + (tid & 7) * 8;
        const float* wsrc0 = w + (size_t)(tid >> 3) * Dm + (tid & 7) * 8;
        const float* wsrc1 = wsrc0 + 32 * (size_t)Dm;
        float* adst = &Al[tid >> 3][(tid & 7) * 8];
        float* wdst0 = &Wl[tid >> 3][(tid & 7) * 8];
        float* wdst1 = &Wl[32 + (tid >> 3)][(tid & 7) * 8];

        float4 acc0 = make_float4(0.f, 0.f, 0.f, 0.f);  // tok rt,   exp ce..+3
        float4 acc1 = make_float4(0.f, 0.f, 0.f, 0.f);  // tok rt+1, exp ce..+3

        // 2-deep prefetch: set p = even chunks, set q = odd chunks
        float4 pa0 = *(const float4*)(asrc + 0);
        float4 pa1 = *(const float4*)(asrc + 4);
        float4 pw0 = *(const float4*)(wsrc0 + 0);
        float4 pw1 = *(const float4*)(wsrc0 + 4);
        float4 pw2 = *(const float4*)(wsrc1 + 0);
        float4 pw3 = *(const float4*)(wsrc1 + 4);
        float4 qa0 = *(const float4*)(asrc + 64);
        float4 qa1 = *(const float4*)(asrc + 68);
        float4 qw0 = *(const float4*)(wsrc0 + 64);
        float4 qw1 = *(const float4*)(wsrc0 + 68);
        float4 qw2 = *(const float4*)(wsrc1 + 64);
        float4 qw3 = *(const float4*)(wsrc1 + 68);

#define INNER_COMPUTE                                                          \
        _Pragma("unroll 4")                                                    \
        for (int k4 = 0; k4 < 16; ++k4) {                                      \
            float4 a0 = *(const float4*)&Al[rt][k4 * 4];                       \
            float4 a1 = *(const float4*)&Al[rt + 1][k4 * 4];                   \
            float4 w0 = *(const float4*)&Wl[ce + 0][k4 * 4];                   \
            float4 w1 = *(const float4*)&Wl[ce + 1][k4 * 4];                   \
            float4 w2 = *(const float4*)&Wl[ce + 2][k4 * 4];                   \
            float4 w3 = *(const float4*)&Wl[ce + 3][k4 * 4];                   \
            acc0.x = fmaf(a0.w, w0.w, fmaf(a0.z, w0.z, fmaf(a0.y, w0.y, fmaf(a0.x, w0.x, acc0.x)))); \
            acc0.y = fmaf(a0.w, w1.w, fmaf(a0.z, w1.z, fmaf(a0.y, w1.y, fmaf(a0.x, w1.x, acc0.y)))); \
            acc0.z = fmaf(a0.w, w2.w, fmaf(a0.z, w2.z, fmaf(a0.y, w2.y, fmaf(a0.x, w2.x, acc0.z)))); \
            acc0.w = fmaf(a0.w, w3.w, fmaf(a0.z, w3.z, fmaf(a0.y, w3.y, fmaf(a0.x, w3.x, acc0.w)))); \
            acc1.x = fmaf(a1.w, w0.w, fmaf(a1.z, w0.z, fmaf(a1.y, w0.y, fmaf(a1.x, w0.x, acc1.x)))); \
            acc1.y = fmaf(a1.w, w1.w, fmaf(a1.z, w1.z, fmaf(a1.y, w1.y, fmaf(a1.x, w1.x, acc1.y)))); \
            acc1.z = fmaf(a1.w, w2.w, fmaf(a1.z, w2.z, fmaf(a1.y, w2.y, fmaf(a1.x, w2.x, acc1.z)))); \
            acc1.w = fmaf(a1.w, w3.w, fmaf(a1.z, w3.z, fmaf(a1.y, w3.y, fmaf(a1.x, w3.x, acc1.w)))); \
        }

        for (int ch = 0; ch < 16; ch += 2) {
            // ---- even chunk: regs(p) -> LDS, refill p for ch+2, compute ----
            __syncthreads();
            *(float4*)(adst + 0) = pa0;  *(float4*)(adst + 4) = pa1;
            *(float4*)(wdst0 + 0) = pw0; *(float4*)(wdst0 + 4) = pw1;
            *(float4*)(wdst1 + 0) = pw2; *(float4*)(wdst1 + 4) = pw3;
            __syncthreads();
            if (ch + 2 < 16) {
                int kb = (ch + 2) * 64;
                pa0 = *(const float4*)(asrc + kb);
                pa1 = *(const float4*)(asrc + kb + 4);
                pw0 = *(const float4*)(wsrc0 + kb);
                pw1 = *(const float4*)(wsrc0 + kb + 4);
                pw2 = *(const float4*)(wsrc1 + kb);
                pw3 = *(const float4*)(wsrc1 + kb + 4);
            }
            INNER_COMPUTE
            // ---- odd chunk: regs(q) -> LDS, refill q for ch+3, compute ----
            __syncthreads();
            *(float4*)(adst + 0) = qa0;  *(float4*)(adst + 4) = qa1;
            *(float4*)(wdst0 + 0) = qw0; *(float4*)(wdst0 + 4) = qw1;
            *(float4*)(wdst1 + 0) = qw2; *(float4*)(wdst1 + 4) = qw3;
            __syncthreads();
            if (ch + 3 < 16) {
                int kb = (ch + 3) * 64;
                qa0 = *(const float4*)(asrc + kb);
                qa1 = *(const float4*)(asrc + kb + 4);
                qw0 = *(const float4*)(wsrc0 + kb);
                qw1 = *(const float4*)(wsrc0 + kb + 4);
                qw2 = *(const float4*)(wsrc1 + kb);
                qw3 = *(const float4*)(wsrc1 + kb + 4);
            }
            INNER_COMPUTE
        }
#undef INNER_COMPUTE
        __syncthreads();
        // ---- epilogue: logits tile -> LDS (reuse Al), softmax/argmax ----
        Al[rt][ce + 0] = acc0.x; Al[rt][ce + 1] = acc0.y;
        Al[rt][ce + 2] = acc0.z; Al[rt][ce + 3] = acc0.w;
        Al[rt + 1][ce + 0] = acc1.x; Al[rt + 1][ce + 1] = acc1.y;
        Al[rt + 1][ce + 2] = acc1.z; Al[rt + 1][ce + 3] = acc1.w;
        __syncthreads();
        if (tid < 32) {   // row phase: first-index argmax + exp-sum
            float m = Al[tid][0];
            int am = 0;
#pragma unroll
            for (int c = 1; c < E; ++c) {
                float v = Al[tid][c];
                if (v > m) { m = v; am = c; }
            }
            float ssum = 0.f;
#pragma unroll
            for (int c = 0; c < E; ++c) ssum += __expf(Al[tid][c] - m);
            float inv = 1.0f / ssum;   // softmax value at the argmax
            gate[t0 + tid] = inv;
            idx[t0 + tid] = am;
            sm[tid] = m;
            sinv[tid] = inv;
        }
        __syncthreads();
        if (tid < E) {    // column phase: partial me sums (deterministic)
            float cs = 0.f;
#pragma unroll 8
            for (int r = 0; r < 32; ++r)
                cs += __expf(Al[r][tid] - sm[r]) * sinv[r];
            me_part[bid * E + tid] = cs;
        }
    } else {
        int fb = bid - GEMM_BLOCKS;
        f32x4 z = {0.f, 0.f, 0.f, 0.f};
        f32x4* o4 = (f32x4*)out;
        for (unsigned i = (unsigned)fb * 256u + tid; i < N4ALL;
             i += FILL_BLOCKS * 256u)
            o4[i] = z;
    }
}

// ---------------- K2: ordered scan + scatter + counts + me-reduce + l_aux ----
// R8's proven kernel, verbatim. 64 blocks (one per expert) x 256 threads.
__global__ __launch_bounds__(256) void k_scan(const int* __restrict__ idx,
                                              const float* __restrict__ gate,
                                              const float* __restrict__ me_part,
                                              float* __restrict__ out) {
    int e = blockIdx.x;
    int tid = threadIdx.x;
    int lane = tid & 63;
    int wid = tid >> 6;
    __shared__ int wsum[4];
    __shared__ float red[256];
    int running = 0;
    for (int ch = 0; ch < S / 256; ++ch) {
        int t = ch * 256 + tid;
        bool f = (idx[t] == e);
        unsigned long long b = __ballot(f);
        int pre = __popcll(b & ((1ull << lane) - 1ull));
        if (lane == 0) wsum[wid] = __popcll(b);
        __syncthreads();
        int off = running;
#pragma unroll
        for (int w2 = 0; w2 < 4; ++w2)
            if (w2 < wid) off += wsum[w2];
        int p = off + pre;
        if (f && p < CAP) {
            size_t o = 1 + (size_t)t * (E * CAP) + (size_t)e * CAP + (size_t)p;
            out[o] = gate[t];                 // combine_weights
            out[o + (size_t)SEC] = 1.0f;      // dispatch_mask
        }
        running += wsum[0] + wsum[1] + wsum[2] + wsum[3];
        __syncthreads();
    }
    // me reduction: me_sum[e] = sum over 256 GEMM blocks' partials
    red[tid] = me_part[tid * E + e];
    __syncthreads();
    for (int s2 = 128; s2 > 0; s2 >>= 1) {
        if (tid < s2) red[tid] += red[tid + s2];
        __syncthreads();
    }
    if (tid == 0) {
        out[1 + 2 * (size_t)SEC + e] = (float)running;   // exp_counts (pre-drop)
        float la = red[0] * (1.0f / (float)S) *
                   ((float)running / (float)S) * (float)E;
        atomicAdd(out, la);                              // l_aux
    }
}

extern "C" void kernel_launch(void* const* d_in, const int* in_sizes, int n_in,
                              void* d_out, int out_size, void* d_ws, size_t ws_size,
                              hipStream_t stream) {
    const float* x = (const float*)d_in[0];      // [S, Dm] fp32
    const float* w = (const float*)d_in[1];      // [E, Dm] fp32
    float* out = (float*)d_out;

    // ws layout
    float* me_part = (float*)d_ws;               // [256][64] = 64 KB
    float* gate = me_part + GEMM_BLOCKS * E;     // S floats
    int* idx = (int*)(gate + S);                 // S ints

    k_main<<<dim3(GEMM_BLOCKS + FILL_BLOCKS), dim3(256), 0, stream>>>(
        x, w, gate, idx, me_part, out);
    k_scan<<<dim3(64), dim3(256), 0, stream>>>(idx, gate, me_part, out);
}